// Round 1
// baseline (1080.937 us; speedup 1.0000x reference)
//
#include <hip/hip_runtime.h>
#include <stdint.h>

#define S_TOK 2048
#define D_NEU 11008
#define H_OUT 4096
#define K_TOK 3302
#define BASE_N 2201
#define K2_SEL 2201
#define NSEL 4402

typedef __attribute__((ext_vector_type(8))) short short8;
typedef __attribute__((ext_vector_type(4))) float float4v;

__device__ __forceinline__ short f2bf(float x) {
  uint32_t u = __float_as_uint(x);
  u += 0x7FFFu + ((u >> 16) & 1u);
  return (short)(u >> 16);
}

// ---------------- fp32 -> bf16 bulk convert ----------------
__global__ __launch_bounds__(256) void cvt_bf16(const float* __restrict__ in,
                                                short* __restrict__ out, size_t n) {
  size_t stride = (size_t)gridDim.x * blockDim.x * 4;
  for (size_t i = ((size_t)blockIdx.x * blockDim.x + threadIdx.x) * 4; i < n; i += stride) {
    float4v v = *(const float4v*)(in + i);
    short o0 = f2bf(v[0]), o1 = f2bf(v[1]), o2 = f2bf(v[2]), o3 = f2bf(v[3]);
    short* p = out + i;
    p[0] = o0; p[1] = o1; p[2] = o2; p[3] = o3;
  }
}

// ---------------- per-token exact top-k membership counts ----------------
// One block per token. Exact k-th largest via 4x8-bit radix select on
// monotone-mapped uint32, then membership with jax.lax.top_k tie semantics
// (ties at the threshold value filled by LOWEST index first).
__global__ __launch_bounds__(256) void topk_count(const float* __restrict__ x,
                                                  int* __restrict__ counts,
                                                  short* __restrict__ xb) {
  __shared__ uint32_t u[D_NEU];     // 44032 B
  __shared__ uint32_t hist[256];
  __shared__ uint32_t sh_sel, sh_kr, sh_e;
  __shared__ int eq_list[1024];
  __shared__ int eq_n;
  const int t = blockIdx.x;
  const int tid = threadIdx.x;
  const float* row = x + (size_t)t * D_NEU;

  for (int i = tid; i < D_NEU; i += 256) {
    float f = row[i];
    uint32_t b = __float_as_uint(f);
    u[i] = (b & 0x80000000u) ? ~b : (b | 0x80000000u);
    if (xb) xb[(size_t)t * D_NEU + i] = f2bf(f);   // fused x->bf16
  }

  uint32_t prefix = 0, kr = K_TOK;
  for (int shift = 24; shift >= 0; shift -= 8) {
    uint32_t mask_hi = (shift == 24) ? 0u : (0xFFFFFFFFu << (shift + 8));
    hist[tid] = 0;  // 256 threads, 256 bins
    __syncthreads();
    for (int i = tid; i < D_NEU; i += 256) {
      uint32_t v = u[i];
      if ((v & mask_hi) == prefix) atomicAdd(&hist[(v >> shift) & 255u], 1u);
    }
    __syncthreads();
    if (tid == 0) {
      uint32_t c = 0; int sel = 0;
      for (int b = 255; b >= 0; --b) {
        uint32_t nc = c + hist[b];
        if (nc >= kr) { sel = b; break; }
        c = nc;
      }
      sh_sel = (uint32_t)sel; sh_kr = kr - c; sh_e = hist[sel];
    }
    __syncthreads();
    prefix |= sh_sel << (uint32_t)shift;
    kr = sh_kr;
    __syncthreads();
  }
  const uint32_t v = prefix;     // exact k-th largest (mapped)
  const uint32_t ties = kr;      // # of equal-valued entries included
  const uint32_t e = sh_e;       // total equal-valued entries

  if (ties == e) {
    for (int i = tid; i < D_NEU; i += 256)
      if (u[i] >= v) atomicAdd(&counts[i], 1);
  } else {
    if (tid == 0) eq_n = 0;
    __syncthreads();
    for (int i = tid; i < D_NEU; i += 256) {
      uint32_t ui = u[i];
      if (ui > v) atomicAdd(&counts[i], 1);
      else if (ui == v) { int p = atomicAdd(&eq_n, 1); if (p < 1024) eq_list[p] = i; }
    }
    __syncthreads();
    int ne = eq_n < 1024 ? eq_n : 1024;
    for (int j = tid; j < ne; j += 256) {
      int me = eq_list[j]; uint32_t r = 0;
      for (int o = 0; o < ne; ++o) r += (eq_list[o] < me) ? 1u : 0u;
      if (r < ties) atomicAdd(&counts[me], 1);
    }
  }
}

// ---------------- rank candidates (count desc, id asc), emit idx_all ----------------
__global__ __launch_bounds__(1024) void rank_select(const int* __restrict__ counts,
                                                    int* __restrict__ idx_all) {
  __shared__ uint32_t key[16384];   // 64 KB
  const int tid = threadIdx.x;
  const int NC = D_NEU - BASE_N;    // 8807
  for (int i = tid; i < 16384; i += 1024) {
    uint32_t kv = 0;
    if (i < NC) {
      int d = BASE_N + i;
      kv = ((((uint32_t)counts[d]) << 14) | (uint32_t)(D_NEU - 1 - d)) + 1u;
    }
    key[i] = kv;
  }
  __syncthreads();
  for (unsigned size = 2; size <= 16384u; size <<= 1) {
    for (unsigned stride = size >> 1; stride > 0; stride >>= 1) {
      for (unsigned t = tid; t < 8192u; t += 1024u) {
        unsigned lo = ((t & ~(stride - 1u)) << 1) | (t & (stride - 1u));
        unsigned hi = lo + stride;
        uint32_t a = key[lo], b = key[hi];
        bool desc = ((lo & size) == 0u);
        if (desc ? (a < b) : (a > b)) { key[lo] = b; key[hi] = a; }
      }
      __syncthreads();
    }
  }
  for (int j = tid; j < BASE_N; j += 1024) idx_all[j] = j;
  for (int j = tid; j < K2_SEL; j += 1024)
    idx_all[BASE_N + j] = (D_NEU - 1) - (int)((key[j] - 1u) & 0x3FFFu);
}

// ---------------- gather filtered_W (exact fp32) ----------------
__global__ __launch_bounds__(256) void gather_w(const float* __restrict__ W,
                                                const int* __restrict__ idx_all,
                                                float* __restrict__ out2) {
  int j = blockIdx.x * 256 + threadIdx.x;
  int h = blockIdx.y;
  if (j < NSEL) out2[(size_t)h * NSEL + j] = W[(size_t)h * D_NEU + idx_all[j]];
}

// ---------------- bf16 MFMA GEMM: C[s,h] = sum_k A[s,k]*B[h,k] ----------------
#define BM 128
#define BN 128
#define BKK 32

template <int FROM_FP32>
__global__ __launch_bounds__(256) void gemm_bt(const void* __restrict__ Av,
                                               const void* __restrict__ Bv,
                                               float* __restrict__ C) {
  __shared__ __align__(16) short As[BM * BKK];   // 8 KB
  __shared__ __align__(16) short Bs[BN * BKK];   // 8 KB
  const int tid = threadIdx.x;
  const int bm = blockIdx.y * BM;
  const int bn = blockIdx.x * BN;
  const int wave = tid >> 6, lane = tid & 63;
  const int wm = (wave >> 1) * 64, wn = (wave & 1) * 64;
  const int quad = lane >> 4, l16 = lane & 15;
  float4v acc[4][4];
  #pragma unroll
  for (int i = 0; i < 4; ++i)
    #pragma unroll
    for (int j = 0; j < 4; ++j) acc[i][j] = (float4v){0.f, 0.f, 0.f, 0.f};

  for (int k0 = 0; k0 < D_NEU; k0 += BKK) {
    if (FROM_FP32) {
      const float* A = (const float*)Av;
      const float* B = (const float*)Bv;
      #pragma unroll
      for (int c = 0; c < 2; ++c) {
        int f = tid + c * 256;            // 16B LDS chunk id (512 per tile)
        int r = f >> 2, cp = f & 3;       // row, 8-elem chunk within row
        const float* sa = A + (size_t)(bm + r) * D_NEU + k0 + cp * 8;
        float4v v0 = *(const float4v*)sa;
        float4v v1 = *(const float4v*)(sa + 4);
        short8 o;
        o[0]=f2bf(v0[0]); o[1]=f2bf(v0[1]); o[2]=f2bf(v0[2]); o[3]=f2bf(v0[3]);
        o[4]=f2bf(v1[0]); o[5]=f2bf(v1[1]); o[6]=f2bf(v1[2]); o[7]=f2bf(v1[3]);
        *(short8*)&As[f * 8] = o;
        const float* sb = B + (size_t)(bn + r) * D_NEU + k0 + cp * 8;
        v0 = *(const float4v*)sb; v1 = *(const float4v*)(sb + 4);
        o[0]=f2bf(v0[0]); o[1]=f2bf(v0[1]); o[2]=f2bf(v0[2]); o[3]=f2bf(v0[3]);
        o[4]=f2bf(v1[0]); o[5]=f2bf(v1[1]); o[6]=f2bf(v1[2]); o[7]=f2bf(v1[3]);
        *(short8*)&Bs[f * 8] = o;
      }
    } else {
      const short* A = (const short*)Av;
      const short* B = (const short*)Bv;
      #pragma unroll
      for (int c = 0; c < 2; ++c) {
        int f = tid + c * 256;
        int r = f >> 2, cp = f & 3;
        __builtin_amdgcn_global_load_lds(
            (const __attribute__((address_space(1))) void*)(A + (size_t)(bm + r) * D_NEU + k0 + cp * 8),
            (__attribute__((address_space(3))) void*)&As[f * 8], 16, 0, 0);
        __builtin_amdgcn_global_load_lds(
            (const __attribute__((address_space(1))) void*)(B + (size_t)(bn + r) * D_NEU + k0 + cp * 8),
            (__attribute__((address_space(3))) void*)&Bs[f * 8], 16, 0, 0);
      }
    }
    __syncthreads();
    short8 af[4], bfv[4];
    #pragma unroll
    for (int i = 0; i < 4; ++i) {
      af[i]  = *(const short8*)&As[(wm + i * 16 + l16) * BKK + quad * 8];
      bfv[i] = *(const short8*)&Bs[(wn + i * 16 + l16) * BKK + quad * 8];
    }
    #pragma unroll
    for (int i = 0; i < 4; ++i)
      #pragma unroll
      for (int j = 0; j < 4; ++j)
        acc[i][j] = __builtin_amdgcn_mfma_f32_16x16x32_bf16(af[i], bfv[j], acc[i][j], 0, 0, 0);
    __syncthreads();
  }
  // C/D layout: col = lane&15, row = quad*4 + reg  [m89-verified]
  #pragma unroll
  for (int i = 0; i < 4; ++i)
    #pragma unroll
    for (int j = 0; j < 4; ++j)
      #pragma unroll
      for (int r = 0; r < 4; ++r)
        C[(size_t)(bm + wm + i * 16 + quad * 4 + r) * H_OUT + (bn + wn + j * 16 + l16)] =
            acc[i][j][r];
}

extern "C" void kernel_launch(void* const* d_in, const int* in_sizes, int n_in,
                              void* d_out, int out_size, void* d_ws, size_t ws_size,
                              hipStream_t stream) {
  (void)in_sizes; (void)n_in; (void)out_size;
  const float* x = (const float*)d_in[0];   // [1, 2048, 11008]
  const float* W = (const float*)d_in[1];   // [4096, 11008]
  float* out1 = (float*)d_out;                       // true_value [2048*4096]
  float* out2 = out1 + (size_t)S_TOK * H_OUT;        // filtered_W [4096*4402]

  uint8_t* ws = (uint8_t*)d_ws;
  int* counts  = (int*)ws;                  // 44032 B
  int* idx_all = (int*)(ws + 44032);        // 17608 B
  short* xb = (short*)(ws + 65536);                       // S*D bf16
  short* Wb = (short*)(ws + 65536 + (size_t)S_TOK * D_NEU * 2);  // H*D bf16
  const size_t needA = 65536 + ((size_t)S_TOK + H_OUT) * D_NEU * 2;
  const bool pathA = ws_size >= needA;

  hipMemsetAsync(counts, 0, D_NEU * sizeof(int), stream);
  if (pathA) {
    cvt_bf16<<<4096, 256, 0, stream>>>(W, Wb, (size_t)H_OUT * D_NEU);
    topk_count<<<S_TOK, 256, 0, stream>>>(x, counts, xb);
  } else {
    topk_count<<<S_TOK, 256, 0, stream>>>(x, counts, nullptr);
  }
  rank_select<<<1, 1024, 0, stream>>>(counts, idx_all);
  gather_w<<<dim3((NSEL + 255) / 256, H_OUT), 256, 0, stream>>>(W, idx_all, out2);
  if (pathA)
    gemm_bt<0><<<dim3(H_OUT / BN, S_TOK / BM), 256, 0, stream>>>(xb, Wb, out1);
  else
    gemm_bt<1><<<dim3(H_OUT / BN, S_TOK / BM), 256, 0, stream>>>(x, W, out1);
}

// Round 2
// 1056.398 us; speedup vs baseline: 1.0232x; 1.0232x over previous
//
#include <hip/hip_runtime.h>
#include <stdint.h>

#define S_TOK 2048
#define D_NEU 11008
#define H_OUT 4096
#define K_TOK 3302
#define BASE_N 2201
#define K2_SEL 2201
#define NSEL 4402
#define NWORD 172          // D_NEU / 64

typedef __attribute__((ext_vector_type(8))) short short8;
typedef __attribute__((ext_vector_type(4))) short short4v;
typedef __attribute__((ext_vector_type(4))) float float4v;
typedef __attribute__((ext_vector_type(4))) unsigned int uint4v;
typedef unsigned long long u64;

__device__ __forceinline__ short f2bf(float x) {
  uint32_t u = __float_as_uint(x);
  u += 0x7FFFu + ((u >> 16) & 1u);
  return (short)(u >> 16);
}
__device__ __forceinline__ uint32_t fmap(float f) {
  uint32_t b = __float_as_uint(f);
  return (b & 0x80000000u) ? ~b : (b | 0x80000000u);
}

// ---------------- per-token exact top-k -> membership bitmask ----------------
// One block/token. Exact k-th largest via 32-step bisection on monotone-mapped
// uint32 (register counts, shuffle+LDS reduce, ZERO atomics). Membership with
// jax.lax.top_k tie semantics (ties filled by lowest index), emitted as a
// 64-bit ballot per 64 neurons. Also fuses x -> bf16.
__global__ __launch_bounds__(256) void topk_count(const float* __restrict__ x,
                                                  u64* __restrict__ bitmask,
                                                  short* __restrict__ xb) {
  __shared__ uint32_t u[D_NEU];     // 44032 B
  __shared__ int red[4];
  const int t = blockIdx.x;
  const int tid = threadIdx.x;
  const int lane = tid & 63, wv = tid >> 6;
  const float* row = x + (size_t)t * D_NEU;

  uint32_t uv[44];
  #pragma unroll
  for (int j = 0; j < 11; ++j) {
    int i4 = tid + j * 256;               // float4 index, 2752 total
    uv[j*4+0] = uv[j*4+1] = uv[j*4+2] = uv[j*4+3] = 0u;   // sentinel (< any probed mid)
    if (i4 < 2752) {
      float4v v = ((const float4v*)row)[i4];
      uint4v m;
      #pragma unroll
      for (int c = 0; c < 4; ++c) { m[c] = fmap(v[c]); uv[j*4+c] = m[c]; }
      *(uint4v*)&u[i4 * 4] = m;
      if (xb) {
        short4v o;
        #pragma unroll
        for (int c = 0; c < 4; ++c) o[c] = f2bf(v[c]);
        *(short4v*)(xb + (size_t)t * D_NEU + i4 * 4) = o;
      }
    }
  }

  // block-wide count of {uv >= T}; 2 barriers, no atomics
  auto cnt_ge = [&](uint32_t T) -> int {
    int c = 0;
    #pragma unroll
    for (int j = 0; j < 44; ++j) c += (uv[j] >= T) ? 1 : 0;
    #pragma unroll
    for (int off = 32; off; off >>= 1) c += __shfl_down(c, off);
    if (lane == 0) red[wv] = c;
    __syncthreads();
    int tot = red[0] + red[1] + red[2] + red[3];
    __syncthreads();
    return tot;
  };

  uint32_t lo = 0u, hi = 0xFFFFFFFFu;   // cnt_ge(lo)>=K, cnt_ge(hi)<K
  while (hi - lo > 1u) {
    uint32_t mid = lo + ((hi - lo) >> 1);
    if (cnt_ge(mid) >= K_TOK) lo = mid; else hi = mid;
  }
  const uint32_t vstar = lo;                    // exact k-th largest (mapped)
  const int cnt_gt = cnt_ge(vstar + 1u);
  const int ties = K_TOK - cnt_gt;              // equals to include
  const int e = cnt_ge(vstar) - cnt_gt;         // total equals
  const bool tie_all = (ties == e);

  // ballot membership: wave wv covers words [wv*43, wv*43+43)
  for (int w = wv * 43; w < wv * 43 + 43; ++w) {
    uint32_t uu = u[w * 64 + lane];
    bool m = false;
    if (uu > vstar) m = true;
    else if (uu == vstar) {
      if (tie_all) m = true;
      else {                                    // rare exact-tie path
        int idx = w * 64 + lane, r = 0;
        for (int i = 0; i < idx; ++i) r += (u[i] == vstar) ? 1 : 0;
        m = (r < ties);
      }
    }
    u64 mask = __ballot(m);
    if (lane == 0) bitmask[(size_t)w * S_TOK + t] = mask;
  }
}

// ---------------- counts[d] = sum_t bit(t,d) ----------------
__global__ __launch_bounds__(256) void count_bits(const u64* __restrict__ bitmask,
                                                  int* __restrict__ counts) {
  __shared__ u64 m[S_TOK];        // 16 KB
  __shared__ int partial[4][64];
  const int w = blockIdx.x, tid = threadIdx.x;
  for (int i = tid; i < S_TOK; i += 256) m[i] = bitmask[(size_t)w * S_TOK + i];
  __syncthreads();
  const int b = tid & 63, part = tid >> 6;
  int c = 0;
  for (int t = part * 512; t < part * 512 + 512; ++t) c += (int)((m[t] >> b) & 1ull);
  partial[part][b] = c;
  __syncthreads();
  if (tid < 64)
    counts[w * 64 + tid] = partial[0][tid] + partial[1][tid] + partial[2][tid] + partial[3][tid];
}

// ---------------- rank candidates, select top-2201, emit idx_all ----------------
// keys are DISTINCT (count<<14 | reversed-id)+1, so the 2201st-largest key is
// found by bisection, the winners compacted, and only 4096 sorted bitonically.
__global__ __launch_bounds__(1024) void rank_select(const int* __restrict__ counts,
                                                    int* __restrict__ idx_all) {
  __shared__ uint32_t cand[4096];   // 16 KB
  __shared__ int red[16];
  __shared__ int cnt_sh;
  const int tid = threadIdx.x, lane = tid & 63, wv = tid >> 6;
  const int NC = D_NEU - BASE_N;    // 8807
  uint32_t kv[9];
  #pragma unroll
  for (int j = 0; j < 9; ++j) {
    int i = tid + j * 1024;
    kv[j] = 0u;
    if (i < NC) {
      int d = BASE_N + i;
      kv[j] = ((((uint32_t)counts[d]) << 14) | (uint32_t)(D_NEU - 1 - d)) + 1u;
    }
  }
  auto cnt_ge = [&](uint32_t T) -> int {
    int c = 0;
    #pragma unroll
    for (int j = 0; j < 9; ++j) c += (kv[j] >= T) ? 1 : 0;
    #pragma unroll
    for (int off = 32; off; off >>= 1) c += __shfl_down(c, off);
    if (lane == 0) red[wv] = c;
    __syncthreads();
    int tot = 0;
    #pragma unroll
    for (int k = 0; k < 16; ++k) tot += red[k];
    __syncthreads();
    return tot;
  };
  uint32_t lo = 0u, hi = 1u << 26;
  while (hi - lo > 1u) {
    uint32_t mid = lo + ((hi - lo) >> 1);
    if (cnt_ge(mid) >= K2_SEL) lo = mid; else hi = mid;
  }
  if (tid == 0) cnt_sh = 0;
  for (int i = tid; i < 4096; i += 1024) cand[i] = 0u;
  __syncthreads();
  #pragma unroll
  for (int j = 0; j < 9; ++j)
    if (kv[j] >= lo && kv[j] != 0u) { int p = atomicAdd(&cnt_sh, 1); cand[p] = kv[j]; }
  __syncthreads();
  // bitonic sort 4096 descending
  for (unsigned size = 2; size <= 4096u; size <<= 1) {
    for (unsigned stride = size >> 1; stride > 0; stride >>= 1) {
      #pragma unroll
      for (unsigned tt = tid; tt < 2048u; tt += 1024u) {
        unsigned li = ((tt & ~(stride - 1u)) << 1) | (tt & (stride - 1u));
        unsigned hi2 = li + stride;
        uint32_t a = cand[li], b = cand[hi2];
        bool desc = ((li & size) == 0u);
        if (desc ? (a < b) : (a > b)) { cand[li] = b; cand[hi2] = a; }
      }
      __syncthreads();
    }
  }
  for (int j = tid; j < BASE_N; j += 1024) idx_all[j] = j;
  for (int j = tid; j < K2_SEL; j += 1024)
    idx_all[BASE_N + j] = (D_NEU - 1) - (int)((cand[j] - 1u) & 0x3FFFu);
}

// ---------------- fused W pass: W->bf16 + gather filtered_W ----------------
__global__ __launch_bounds__(256) void fused_w(const float* __restrict__ W,
                                               const int* __restrict__ idx_all,
                                               short* __restrict__ Wb,
                                               float* __restrict__ out2) {
  __shared__ float row[D_NEU];    // 44 KB
  const int h = blockIdx.x, tid = threadIdx.x;
  const float* src = W + (size_t)h * D_NEU;
  #pragma unroll
  for (int j = 0; j < 11; ++j) {
    int i4 = tid + j * 256;
    if (i4 < 2752) {
      float4v v = ((const float4v*)src)[i4];
      *(float4v*)&row[i4 * 4] = v;
      if (Wb) {
        short4v o;
        #pragma unroll
        for (int c = 0; c < 4; ++c) o[c] = f2bf(v[c]);
        *(short4v*)(Wb + (size_t)h * D_NEU + i4 * 4) = o;
      }
    }
  }
  __syncthreads();
  for (int j = tid; j < NSEL; j += 256)
    out2[(size_t)h * NSEL + j] = row[idx_all[j]];
}

// ---------------- bf16 MFMA GEMM, split-K=2, XOR chunk-swizzle ----------------
#define BM 128
#define BN 128
#define BKK 32
#define KSPLIT 2
#define KHALF (D_NEU / KSPLIT)   // 5504 = 172 * 32

template <int FROM_FP32>
__global__ __launch_bounds__(256) void gemm_bt(const void* __restrict__ Av,
                                               const void* __restrict__ Bv,
                                               float* __restrict__ C) {
  __shared__ __align__(16) short As[BM * BKK];   // 8 KB
  __shared__ __align__(16) short Bs[BN * BKK];   // 8 KB
  const int tid = threadIdx.x;
  const int bm = blockIdx.y * BM;
  const int bn = blockIdx.x * BN;
  const int kz = blockIdx.z;
  const int wave = tid >> 6, lane = tid & 63;
  const int wm = (wave >> 1) * 64, wn = (wave & 1) * 64;
  const int quad = lane >> 4, l16 = lane & 15;
  float4v acc[4][4];
  #pragma unroll
  for (int i = 0; i < 4; ++i)
    #pragma unroll
    for (int j = 0; j < 4; ++j) acc[i][j] = (float4v){0.f, 0.f, 0.f, 0.f};

  const int kbeg = kz * KHALF, kend = kbeg + KHALF;
  for (int k0 = kbeg; k0 < kend; k0 += BKK) {
    #pragma unroll
    for (int c = 0; c < 2; ++c) {
      int f = tid + c * 256;            // LDS 16B-slot id (512/tile)
      int r = f >> 2, sl = f & 3;
      int cg = sl ^ (r & 3);            // swizzled global chunk
      if (FROM_FP32) {
        const float* A = (const float*)Av;
        const float* B = (const float*)Bv;
        float4v v0 = *(const float4v*)(A + (size_t)(bm + r) * D_NEU + k0 + cg * 8);
        float4v v1 = *(const float4v*)(A + (size_t)(bm + r) * D_NEU + k0 + cg * 8 + 4);
        short8 o;
        #pragma unroll
        for (int c2 = 0; c2 < 4; ++c2) { o[c2] = f2bf(v0[c2]); o[c2+4] = f2bf(v1[c2]); }
        *(short8*)&As[f * 8] = o;
        v0 = *(const float4v*)(B + (size_t)(bn + r) * D_NEU + k0 + cg * 8);
        v1 = *(const float4v*)(B + (size_t)(bn + r) * D_NEU + k0 + cg * 8 + 4);
        #pragma unroll
        for (int c2 = 0; c2 < 4; ++c2) { o[c2] = f2bf(v0[c2]); o[c2+4] = f2bf(v1[c2]); }
        *(short8*)&Bs[f * 8] = o;
      } else {
        const short* A = (const short*)Av;
        const short* B = (const short*)Bv;
        __builtin_amdgcn_global_load_lds(
            (const __attribute__((address_space(1))) void*)(A + (size_t)(bm + r) * D_NEU + k0 + cg * 8),
            (__attribute__((address_space(3))) void*)&As[f * 8], 16, 0, 0);
        __builtin_amdgcn_global_load_lds(
            (const __attribute__((address_space(1))) void*)(B + (size_t)(bn + r) * D_NEU + k0 + cg * 8),
            (__attribute__((address_space(3))) void*)&Bs[f * 8], 16, 0, 0);
      }
    }
    __syncthreads();
    short8 af[4], bfv[4];
    #pragma unroll
    for (int i = 0; i < 4; ++i) {
      int ra = wm + i * 16 + l16;
      int rb = wn + i * 16 + l16;
      af[i]  = *(const short8*)&As[(ra * 4 + (quad ^ (ra & 3))) * 8];
      bfv[i] = *(const short8*)&Bs[(rb * 4 + (quad ^ (rb & 3))) * 8];
    }
    #pragma unroll
    for (int i = 0; i < 4; ++i)
      #pragma unroll
      for (int j = 0; j < 4; ++j)
        acc[i][j] = __builtin_amdgcn_mfma_f32_16x16x32_bf16(af[i], bfv[j], acc[i][j], 0, 0, 0);
    __syncthreads();
  }
  // C/D layout: col = lane&15, row = quad*4 + reg  [m89-verified]
  #pragma unroll
  for (int i = 0; i < 4; ++i)
    #pragma unroll
    for (int j = 0; j < 4; ++j)
      #pragma unroll
      for (int r = 0; r < 4; ++r)
        unsafeAtomicAdd(
            &C[(size_t)(bm + wm + i * 16 + quad * 4 + r) * H_OUT + (bn + wn + j * 16 + l16)],
            acc[i][j][r]);
}

extern "C" void kernel_launch(void* const* d_in, const int* in_sizes, int n_in,
                              void* d_out, int out_size, void* d_ws, size_t ws_size,
                              hipStream_t stream) {
  (void)in_sizes; (void)n_in; (void)out_size;
  const float* x = (const float*)d_in[0];   // [1, 2048, 11008]
  const float* W = (const float*)d_in[1];   // [4096, 11008]
  float* out1 = (float*)d_out;                       // true_value [2048*4096]
  float* out2 = out1 + (size_t)S_TOK * H_OUT;        // filtered_W [4096*4402]

  uint8_t* ws = (uint8_t*)d_ws;
  int* idx_all = (int*)ws;                              // 17608 B
  int* counts  = (int*)(ws + 17664);                    // 44032 B
  short* xb = (short*)(ws + 65536);                     // 45,088,768 B
  short* Wb = xb + (size_t)S_TOK * D_NEU;               // 90,177,536 B
  const size_t needA = 65536 + ((size_t)S_TOK + H_OUT) * D_NEU * 2;
  const bool pathA = ws_size >= needA;
  // bitmask (2,818,048 B) aliases the Wb region: it is fully consumed by
  // count_bits before fused_w writes Wb (single in-order stream).
  u64* bitmask = pathA ? (u64*)Wb : (u64*)(ws + 65536);

  hipMemsetAsync(out1, 0, (size_t)S_TOK * H_OUT * sizeof(float), stream);
  topk_count<<<S_TOK, 256, 0, stream>>>(x, bitmask, pathA ? xb : nullptr);
  count_bits<<<NWORD, 256, 0, stream>>>(bitmask, counts);
  rank_select<<<1, 1024, 0, stream>>>(counts, idx_all);
  fused_w<<<H_OUT, 256, 0, stream>>>(W, idx_all, pathA ? Wb : nullptr, out2);
  if (pathA)
    gemm_bt<0><<<dim3(H_OUT / BN, S_TOK / BM, KSPLIT), 256, 0, stream>>>(xb, Wb, out1);
  else
    gemm_bt<1><<<dim3(H_OUT / BN, S_TOK / BM, KSPLIT), 256, 0, stream>>>(x, W, out1);
}